// Round 3
// baseline (31.496 us; speedup 1.0000x reference)
//
#include <hip/hip_runtime.h>

// Geometry:
//   x : (1,24,56,56) f32   -> c*3136 + h*56 + w
//   w1: (96,3,21)    f32   -> i*63 + j*21 + k
//   w2: (12,7,21)    f32   -> c*147 + jj*21 + k
//   y : (1,96,56,56) f32   -> i*3136 + h*56 + w
//
// t3r[c,h,w] = x[c,h,(w-1)%56] + x[c+12,h,(w-1)%56]         (roll +1 on width)
// t5[h,w,k]  = sum_{c<12,jj<7} t3r[c,h,w+jj-3] * w2[c,jj,k]  (zero width-pad)
// y[i,h,w]   = sum_{j<3,k<21}  t5[h+j-1,w,k]  * w1[i,j,k]    (zero height-pad)
//
// Single fused kernel: grid (56 h, 4 i-chunks of 24) = 224 blocks -> one
// block per CU, one wave per SIMD. Each block recomputes its 3 t5 rows
// (redundancy ~1160 MACs/thread, cheaper than a second dispatch).

#define NH 56
#define NW 56
#define NC 12
#define NK 21
#define NI 96
#define ICHUNK 24

__global__ __launch_bounds__(256)
void fused_kernel(const float* __restrict__ x,
                  const float* __restrict__ w1,
                  const float* __restrict__ w2,
                  float* __restrict__ y) {
    __shared__ float s_w2[NC * 7 * NK];       // 1764 f32, 7.0 KB
    __shared__ float s_w1[ICHUNK * 63];       // 1512 f32, 6.0 KB
    __shared__ float s_t3[3][NC][NW];         // 2016 f32, 8.1 KB
    __shared__ float s_t5[3][NW * NK];        // 3528 f32, 14.1 KB

    const int h   = blockIdx.x;
    const int i0  = blockIdx.y * ICHUNK;
    const int tid = threadIdx.x;

    // --- stage weights ---
    for (int e = tid; e < NC * 7 * NK; e += 256) s_w2[e] = w2[e];
    for (int e = tid; e < ICHUNK * 63; e += 256) s_w1[e] = w1[i0 * 63 + e];

    // --- stage t3 rows h-1..h+1 (pair-sum + width roll, zero-pad height) ---
    for (int e = tid; e < 3 * NC * NW; e += 256) {
        const int r = e / (NC * NW);
        const int c = (e / NW) % NC;
        const int w = e % NW;
        const int hh = h - 1 + r;
        float v = 0.0f;
        if (hh >= 0 && hh < NH) {
            const int wsrc = (w + NW - 1) % NW;   // roll(+1): out[w] = in[w-1]
            const int base = hh * NW + wsrc;
            v = x[c * 3136 + base] + x[(c + 12) * 3136 + base];
        }
        s_t3[r][c][w] = v;
    }
    __syncthreads();

    // --- stage 1: t5 rows h-1..h+1 ---
    for (int e = tid; e < 3 * NW * NK; e += 256) {
        const int r = e / (NW * NK);
        const int w = (e / NK) % NW;
        const int k = e % NK;
        float acc = 0.0f;
        #pragma unroll
        for (int jj = 0; jj < 7; ++jj) {
            const int ww = w + jj - 3;
            if (ww < 0 || ww >= NW) continue;     // zero width-pad
            #pragma unroll
            for (int c = 0; c < NC; ++c) {
                acc += s_t3[r][c][ww] * s_w2[c * 147 + jj * NK + k];
            }
        }
        s_t5[r][w * NK + k] = acc;
    }
    __syncthreads();

    // --- stage 2: y for 24 output channels ---
    for (int e = tid; e < ICHUNK * NW; e += 256) {
        const int il = e / NW;
        const int w  = e % NW;
        float acc = 0.0f;
        #pragma unroll
        for (int j = 0; j < 3; ++j) {
            const float* __restrict__ tp = &s_t5[j][w * NK];
            const float* __restrict__ wp = &s_w1[il * 63 + j * NK];
            #pragma unroll
            for (int k = 0; k < NK; ++k) acc += tp[k] * wp[k];
        }
        y[(i0 + il) * 3136 + h * NW + w] = acc;
    }
}

extern "C" void kernel_launch(void* const* d_in, const int* in_sizes, int n_in,
                              void* d_out, int out_size, void* d_ws, size_t ws_size,
                              hipStream_t stream) {
    const float* x  = (const float*)d_in[0];
    const float* w1 = (const float*)d_in[1];
    const float* w2 = (const float*)d_in[2];
    float* y = (float*)d_out;
    fused_kernel<<<dim3(NH, NI / ICHUNK), dim3(256), 0, stream>>>(x, w1, w2, y);
}

// Round 4
// 22.603 us; speedup vs baseline: 1.3934x; 1.3934x over previous
//
#include <hip/hip_runtime.h>

// Geometry:
//   x  : (1,24,56,56) f32  -> c*3136 + h*56 + w
//   w1 : (96,3,21)    f32  -> i*63 + j*21 + k
//   w2 : (12,7,21)    f32  -> c*147 + jj*21 + k
//   y  : (1,96,56,56) f32  -> i*3136 + h*56 + w
//   t5T: (21,56,56)   f32 workspace -> k*3136 + h*56 + w   (transposed!)
//
// t3r[c,h,w] = x[c,h,(w-1)%56] + x[c+12,h,(w-1)%56]          (roll +1 width)
// t5[h,w,k]  = sum_{c<12,jj<7} t3r[c,h,w+jj-3] * w2[c,jj,k]   (zero width-pad)
// y[i,h,w]   = sum_{j<3,k<21}  t5[h+j-1,w,k]  * w1[i,j,k]     (zero height-pad)
//
// R3 structure: register accumulators + scalar (wave-uniform) weight loads.
// Kernel A: lane=w owns all 21 k (acc in VGPRs); 84 ds_reads + 1764 FMA/lane.
// Kernel B: lane=w holds 63 t5 values in VGPRs; 756 FMA/lane; no LDS.

#define NH 56
#define NW 56
#define NC 12
#define NK 21
#define NI 96
#define ICH 12   // output channels per block in kernel B (8 chunks)

__global__ __launch_bounds__(64)
void t5_kernel(const float* __restrict__ x,
               const float* __restrict__ w2,
               float* __restrict__ t5T) {
    __shared__ float s_t3[NC][NW + 6];     // p = 0..61 <-> ww = p-3 (zero-padded)

    const int h    = blockIdx.x;
    const int lane = threadIdx.x;

    // stage rolled+pair-summed t3 row h, width-padded by 3 each side
    for (int e = lane; e < NC * (NW + 6); e += 64) {
        const int c  = e / (NW + 6);
        const int p  = e % (NW + 6);
        const int ww = p - 3;
        float v = 0.0f;
        if (ww >= 0 && ww < NW) {
            const int wsrc = (ww + NW - 1) % NW;   // roll(+1): out[w] = in[w-1]
            const int base = h * NW + wsrc;
            v = x[c * 3136 + base] + x[(c + 12) * 3136 + base];
        }
        s_t3[c][p] = v;
    }
    __syncthreads();

    const int w = lane;
    if (w < NW) {
        float acc[NK];
        #pragma unroll
        for (int k = 0; k < NK; ++k) acc[k] = 0.0f;

        for (int c = 0; c < NC; ++c) {
            float win[7];
            #pragma unroll
            for (int jj = 0; jj < 7; ++jj) win[jj] = s_t3[c][w + jj];
            #pragma unroll
            for (int k = 0; k < NK; ++k) {
                float a = acc[k];
                #pragma unroll
                for (int jj = 0; jj < 7; ++jj) {
                    a += win[jj] * w2[c * 147 + jj * NK + k];   // uniform -> s_load
                }
                acc[k] = a;
            }
        }
        #pragma unroll
        for (int k = 0; k < NK; ++k) {
            t5T[k * 3136 + h * NW + w] = acc[k];    // lane-contiguous store
        }
    }
}

__global__ __launch_bounds__(64)
void y_kernel(const float* __restrict__ t5T,
              const float* __restrict__ w1,
              float* __restrict__ y) {
    const int h  = blockIdx.x;
    const int i0 = blockIdx.y * ICH;
    const int w  = threadIdx.x;
    if (w >= NW) return;                    // no barriers below; safe

    // load the 63 t5 values this (h,w) column needs (rows h-1..h+1, all k)
    float v[3][NK];
    #pragma unroll
    for (int j = 0; j < 3; ++j) {
        const int hh = h - 1 + j;
        const bool in = (hh >= 0 && hh < NH);
        #pragma unroll
        for (int k = 0; k < NK; ++k) {
            v[j][k] = in ? t5T[k * 3136 + hh * NW + w] : 0.0f;  // lane-contiguous
        }
    }

    for (int il = 0; il < ICH; ++il) {
        const int i = i0 + il;
        float acc = 0.0f;
        #pragma unroll
        for (int j = 0; j < 3; ++j) {
            #pragma unroll
            for (int k = 0; k < NK; ++k) {
                acc += v[j][k] * w1[i * 63 + j * NK + k];       // uniform -> s_load
            }
        }
        y[i * 3136 + h * NW + w] = acc;
    }
}

extern "C" void kernel_launch(void* const* d_in, const int* in_sizes, int n_in,
                              void* d_out, int out_size, void* d_ws, size_t ws_size,
                              hipStream_t stream) {
    const float* x  = (const float*)d_in[0];
    const float* w1 = (const float*)d_in[1];
    const float* w2 = (const float*)d_in[2];
    float* y   = (float*)d_out;
    float* t5T = (float*)d_ws;              // 21*56*56*4 = 263 KB

    t5_kernel<<<dim3(NH), dim3(64), 0, stream>>>(x, w2, t5T);
    y_kernel <<<dim3(NH, NI / ICH), dim3(64), 0, stream>>>(t5T, w1, y);
}

// Round 5
// 15.181 us; speedup vs baseline: 2.0746x; 1.4889x over previous
//
#include <hip/hip_runtime.h>

// Geometry:
//   x : (1,24,56,56) f32  -> c*3136 + h*56 + w
//   w1: (96,3,21)    f32  -> i*63 + j*21 + k
//   w2: (12,7,21)    f32  -> c*147 + jj*21 + k
//   y : (1,96,56,56) f32  -> i*3136 + h*56 + w
//
// t3r[c,h,w] = x[c,h,(w-1)%56] + x[c+12,h,(w-1)%56]          (roll +1 width)
// t5[h,w,k]  = sum_{c<12,jj<7} t3r[c,h,w+jj-3] * w2[c,jj,k]   (zero width-pad)
// y[i,h,w]   = sum_{j<3,k<21}  t5[h+j-1,w,k]  * w1[i,j,k]     (zero height-pad)
//
// R4: single dispatch. 56 blocks (one per h) x 1024 threads (16 waves,
// 4/SIMD). Stage 1: waves 0..8 = (row r, k-group of 7); window in VGPRs,
// weights via scalar loads -> ~0.05 LDS ops per MAC (the R2 killer).
// Stage 2: all 16 waves x 6 channels; 63 t5 values in VGPRs per lane.

#define NH 56
#define NW 56
#define NC 12
#define NK 21
#define NI 96

__global__ __launch_bounds__(1024)
void fused_one(const float* __restrict__ x,
               const float* __restrict__ w1,
               const float* __restrict__ w2,
               float* __restrict__ y) {
    __shared__ float s_t3[3][NC][NW + 6];   // 2232 f32, 8.9 KB  (p <-> ww = p-3)
    __shared__ float s_t5[3][NW * NK];      // 3528 f32, 14.1 KB

    const int h    = blockIdx.x;
    const int tid  = threadIdx.x;
    const int wid  = tid >> 6;
    const int lane = tid & 63;

    // --- stage t3 rows h-1..h+1 (pair-sum + width-roll, zero-pad h and w) ---
    for (int e = tid; e < 3 * NC * (NW + 6); e += 1024) {
        const int r = e / (NC * (NW + 6));
        const int c = (e / (NW + 6)) % NC;
        const int p = e % (NW + 6);
        const int hh = h - 1 + r;
        const int ww = p - 3;
        float v = 0.0f;
        if (hh >= 0 && hh < NH && ww >= 0 && ww < NW) {
            const int wsrc = (ww + NW - 1) % NW;   // roll(+1): out[w] = in[w-1]
            const int base = hh * NW + wsrc;
            v = x[c * 3136 + base] + x[(c + 12) * 3136 + base];
        }
        s_t3[r][c][p] = v;
    }
    __syncthreads();

    // --- stage 1: t5 rows h-1..h+1; wave task = (r = wid/3, kgroup = wid%3) ---
    if (wid < 9 && lane < NW) {
        const int r  = wid / 3;
        const int k0 = __builtin_amdgcn_readfirstlane((wid % 3) * 7);
        const int w  = lane;
        float acc[7] = {0.f, 0.f, 0.f, 0.f, 0.f, 0.f, 0.f};
        for (int c = 0; c < NC; ++c) {
            float win[7];
            #pragma unroll
            for (int jj = 0; jj < 7; ++jj) win[jj] = s_t3[r][c][w + jj];
            const float* __restrict__ wp = w2 + c * 147 + k0;   // SGPR base
            #pragma unroll
            for (int kk = 0; kk < 7; ++kk) {
                float a = acc[kk];
                #pragma unroll
                for (int jj = 0; jj < 7; ++jj) a += win[jj] * wp[jj * NK + kk];
                acc[kk] = a;
            }
        }
        #pragma unroll
        for (int kk = 0; kk < 7; ++kk) s_t5[r][w * NK + k0 + kk] = acc[kk];
    }
    __syncthreads();

    // --- stage 2: all 16 waves, 6 output channels each ---
    if (lane < NW) {
        const int w = lane;
        float v[3][NK];
        #pragma unroll
        for (int j = 0; j < 3; ++j) {
            #pragma unroll
            for (int k = 0; k < NK; ++k) v[j][k] = s_t5[j][w * NK + k];
        }
        const int ibase = __builtin_amdgcn_readfirstlane(wid * 6);
        #pragma unroll
        for (int il = 0; il < 6; ++il) {
            const int i = ibase + il;
            const float* __restrict__ wp = w1 + i * 63;         // SGPR base
            float acc = 0.0f;
            #pragma unroll
            for (int j = 0; j < 3; ++j) {
                #pragma unroll
                for (int k = 0; k < NK; ++k) acc += v[j][k] * wp[j * NK + k];
            }
            y[i * 3136 + h * NW + w] = acc;
        }
    }
}

extern "C" void kernel_launch(void* const* d_in, const int* in_sizes, int n_in,
                              void* d_out, int out_size, void* d_ws, size_t ws_size,
                              hipStream_t stream) {
    const float* x  = (const float*)d_in[0];
    const float* w1 = (const float*)d_in[1];
    const float* w2 = (const float*)d_in[2];
    float* y = (float*)d_out;
    fused_one<<<dim3(NH), dim3(1024), 0, stream>>>(x, w1, w2, y);
}